// Round 1
// baseline (148.277 us; speedup 1.0000x reference)
//
#include <hip/hip_runtime.h>
#include <hip/hip_bf16.h>

typedef __attribute__((ext_vector_type(4))) float f32x4;
typedef __attribute__((ext_vector_type(8))) short bf16x8;

__device__ __forceinline__ unsigned short f2bf(float f) {
    unsigned int u = __float_as_uint(f);
    u = (u + 0x7FFFu + ((u >> 16) & 1u)) >> 16;
    return (unsigned short)u;
}

__device__ __forceinline__ float bf2f(unsigned short u) {
    return __uint_as_float(((unsigned int)u) << 16);
}

__global__ void cvt_weights(const float* __restrict__ W1,
                            const float* __restrict__ W2,
                            unsigned short* __restrict__ W1b,
                            unsigned short* __restrict__ W2b) {
    int i = blockIdx.x * 256 + threadIdx.x;
    if (i < 128 * 256) {
        W1b[i] = f2bf(W1[i]);
        W2b[i] = f2bf(W2[i]);
    }
}

template<bool SRC_BF16>
__device__ __forceinline__ float4 load4(const void* src, int idx, int fo) {
    if constexpr (!SRC_BF16) {
        return *(const float4*)((const float*)src + (size_t)idx * 128 + fo);
    } else {
        ushort4 u = *(const ushort4*)((const unsigned short*)src + (size_t)idx * 128 + fo);
        float4 r;
        r.x = bf2f(u.x); r.y = bf2f(u.y); r.z = bf2f(u.z); r.w = bf2f(u.w);
        return r;
    }
}

// One fused layer: out[m] = relu( [src[self[m]] | mean_s src[neigh[m][s]]] @ W^T )
// M rows per grid, 64 rows per block, K=256, N=128.
template<bool SRC_BF16, bool OUT_BF16>
__global__ __launch_bounds__(256, 2)
void sage_layer(const void* __restrict__ src_v,
                const unsigned short* __restrict__ Wb,   // [128][256] bf16 row-major
                const int* __restrict__ self_idx,        // [M]
                const int* __restrict__ neigh_idx,       // [M][10]
                void* __restrict__ out_v) {
    // 264 = 256 + 8 pad -> row stride 528B (16B aligned, bank stride 4)
    __shared__ unsigned short As[64][264];
    __shared__ int sIdx[64];
    __shared__ int nIdx[64][10];

    const int t = threadIdx.x;
    const int rowBase = blockIdx.x * 64;

    if (t < 64) sIdx[t] = self_idx[rowBase + t];
    for (int i = t; i < 640; i += 256) {
        nIdx[i / 10][i % 10] = neigh_idx[rowBase * 10 + i];
    }
    __syncthreads();

    // Stage combined rows [64][256] as bf16 into LDS.
    // chunk c -> row = c>>6, 4-float chunk cc = c&63 (cc<32: self, else mean of neighbors)
    #pragma unroll
    for (int it = 0; it < 16; ++it) {
        int c = it * 256 + t;
        int row = c >> 6;
        int cc = c & 63;
        float4 v;
        if (cc < 32) {
            v = load4<SRC_BF16>(src_v, sIdx[row], cc * 4);
        } else {
            int fo = (cc - 32) * 4;
            float sx = 0.f, sy = 0.f, sz = 0.f, sw = 0.f;
            #pragma unroll
            for (int sn = 0; sn < 10; ++sn) {
                float4 x = load4<SRC_BF16>(src_v, nIdx[row][sn], fo);
                sx += x.x; sy += x.y; sz += x.z; sw += x.w;
            }
            v.x = sx * 0.1f; v.y = sy * 0.1f; v.z = sz * 0.1f; v.w = sw * 0.1f;
        }
        ushort4 o;
        o.x = f2bf(v.x); o.y = f2bf(v.y); o.z = f2bf(v.z); o.w = f2bf(v.w);
        *(ushort4*)&As[row][cc * 4] = o;
    }
    __syncthreads();

    const int lane = t & 63;
    const int w = t >> 6;
    const int arow = w * 16 + (lane & 15);
    const int ko = (lane >> 4) * 8;
    const int ncol = lane & 15;

    f32x4 acc[8];
    #pragma unroll
    for (int i = 0; i < 8; ++i) acc[i] = (f32x4){0.f, 0.f, 0.f, 0.f};

    #pragma unroll
    for (int kk = 0; kk < 8; ++kk) {
        bf16x8 af = *(const bf16x8*)&As[arow][kk * 32 + ko];
        #pragma unroll
        for (int ct = 0; ct < 8; ++ct) {
            // B[k][n] = W[n][k]; lane needs 8 contiguous k at row n = ct*16 + ncol
            const unsigned short* wp = Wb + (ct * 16 + ncol) * 256 + kk * 32 + ko;
            bf16x8 bf = *(const bf16x8*)wp;
            acc[ct] = __builtin_amdgcn_mfma_f32_16x16x32_bf16(af, bf, acc[ct], 0, 0, 0);
        }
    }

    // C/D: col = lane&15, row = (lane>>4)*4 + r  [verified layout]
    const int mr = rowBase + w * 16 + (lane >> 4) * 4;
    if (OUT_BF16) {
        unsigned short* out = (unsigned short*)out_v;
        #pragma unroll
        for (int ct = 0; ct < 8; ++ct) {
            #pragma unroll
            for (int r = 0; r < 4; ++r) {
                float v = fmaxf(acc[ct][r], 0.f);
                out[(size_t)(mr + r) * 128 + ct * 16 + ncol] = f2bf(v);
            }
        }
    } else {
        float* out = (float*)out_v;
        #pragma unroll
        for (int ct = 0; ct < 8; ++ct) {
            #pragma unroll
            for (int r = 0; r < 4; ++r) {
                float v = fmaxf(acc[ct][r], 0.f);
                out[(size_t)(mr + r) * 128 + ct * 16 + ncol] = v;
            }
        }
    }
}

extern "C" void kernel_launch(void* const* d_in, const int* in_sizes, int n_in,
                              void* d_out, int out_size, void* d_ws, size_t ws_size,
                              hipStream_t stream) {
    const float* raw   = (const float*)d_in[0];   // [200000,128]
    const float* W1    = (const float*)d_in[1];   // [128,256]
    const float* W2    = (const float*)d_in[2];   // [128,256]
    const int* self1   = (const int*)d_in[3];     // [81920]
    const int* neigh1  = (const int*)d_in[4];     // [81920,10]
    const int* self2   = (const int*)d_in[5];     // [8192]
    const int* neigh2  = (const int*)d_in[6];     // [8192,10]
    float* out = (float*)d_out;                   // [8192,128] f32

    char* ws = (char*)d_ws;
    unsigned short* h1  = (unsigned short*)ws;                       // 81920*128 bf16
    unsigned short* W1b = (unsigned short*)(ws + (size_t)81920 * 128 * 2);
    unsigned short* W2b = W1b + 128 * 256;

    cvt_weights<<<128, 256, 0, stream>>>(W1, W2, W1b, W2b);
    sage_layer<false, true><<<81920 / 64, 256, 0, stream>>>(
        (const void*)raw, W1b, self1, neigh1, (void*)h1);
    sage_layer<true, false><<<8192 / 64, 256, 0, stream>>>(
        (const void*)h1, W2b, self2, neigh2, (void*)out);
}

// Round 2
// 110.956 us; speedup vs baseline: 1.3364x; 1.3364x over previous
//
#include <hip/hip_runtime.h>
#include <hip/hip_bf16.h>

typedef __attribute__((ext_vector_type(4))) float f32x4;
typedef __attribute__((ext_vector_type(8))) short bf16x8;

__device__ __forceinline__ unsigned short f2bf(float f) {
    unsigned int u = __float_as_uint(f);
    u = (u + 0x7FFFu + ((u >> 16) & 1u)) >> 16;
    return (unsigned short)u;
}

__device__ __forceinline__ float bf2f(unsigned short u) {
    return __uint_as_float(((unsigned int)u) << 16);
}

__global__ __launch_bounds__(256) void cvt_weights(const float* __restrict__ W1,
                                                   const float* __restrict__ W2,
                                                   unsigned short* __restrict__ W1b,
                                                   unsigned short* __restrict__ W2b) {
    int i = blockIdx.x * 256 + threadIdx.x;
    if (i < 128 * 256) {
        W1b[i] = f2bf(W1[i]);
        W2b[i] = f2bf(W2[i]);
    }
}

// 200000*128 = 25,600,000 elems = 3,200,000 threads x 8 = 12500 blocks x 256
__global__ __launch_bounds__(256) void cvt_feat(const float* __restrict__ in,
                                                unsigned short* __restrict__ out) {
    size_t i = ((size_t)blockIdx.x * 256 + threadIdx.x) * 8;
    float4 a = *(const float4*)(in + i);
    float4 b = *(const float4*)(in + i + 4);
    bf16x8 o;
    o[0] = (short)f2bf(a.x); o[1] = (short)f2bf(a.y);
    o[2] = (short)f2bf(a.z); o[3] = (short)f2bf(a.w);
    o[4] = (short)f2bf(b.x); o[5] = (short)f2bf(b.y);
    o[6] = (short)f2bf(b.z); o[7] = (short)f2bf(b.w);
    *(bf16x8*)(out + i) = o;
}

// Fused layer, bf16 source table: out[m] = relu([src[self[m]] | mean_s src[neigh[m][s]]] @ W^T)
// 64 rows/block, K=256, N=128.
template<bool OUT_BF16>
__global__ __launch_bounds__(256, 4)
void sage_layer_bf(const unsigned short* __restrict__ src,   // [*,128] bf16
                   const unsigned short* __restrict__ Wb,    // [128][256] bf16 row-major
                   const int* __restrict__ self_idx,
                   const int* __restrict__ neigh_idx,
                   void* __restrict__ out_v) {
    __shared__ unsigned short As[64][264];   // combined [self|agg], +8 pad (row 528B)
    __shared__ int sIdx[64];
    __shared__ int nIdxF[640];

    const int t = threadIdx.x;
    const int rowBase = blockIdx.x * 64;

    if (t < 64) sIdx[t] = self_idx[rowBase + t];
    for (int i = t; i < 640; i += 256) nIdxF[i] = neigh_idx[rowBase * 10 + i];
    __syncthreads();

    // Phase A: self rows, full-wave bf16 16B copies. 64 rows x 16 chunks.
    #pragma unroll
    for (int it = 0; it < 4; ++it) {
        int i = it * 256 + t;
        int row = i >> 4, ch = i & 15;
        bf16x8 v = *(const bf16x8*)(src + (size_t)sIdx[row] * 128 + ch * 8);
        *(bf16x8*)&As[row][ch * 8] = v;
    }

    // Phase B: neighbor mean, full-wave: every lane sums 10 independent 16B loads.
    #pragma unroll 2
    for (int it = 0; it < 4; ++it) {
        int i = it * 256 + t;
        int row = i >> 4, ch = i & 15;
        const int co = ch * 8;
        int ni[10];
        #pragma unroll
        for (int sn = 0; sn < 10; ++sn) ni[sn] = nIdxF[row * 10 + sn];
        bf16x8 nv[10];
        #pragma unroll
        for (int sn = 0; sn < 10; ++sn)
            nv[sn] = *(const bf16x8*)(src + (size_t)ni[sn] * 128 + co);
        float s[8];
        #pragma unroll
        for (int e = 0; e < 8; ++e) s[e] = 0.f;
        #pragma unroll
        for (int sn = 0; sn < 10; ++sn) {
            #pragma unroll
            for (int e = 0; e < 8; ++e) s[e] += bf2f((unsigned short)nv[sn][e]);
        }
        bf16x8 o;
        #pragma unroll
        for (int e = 0; e < 8; ++e) o[e] = (short)f2bf(s[e] * 0.1f);
        *(bf16x8*)&As[row][128 + co] = o;
    }
    __syncthreads();

    // MFMA: 4 waves x (16 rows x 128 cols), K=256 via 8 steps of 16x16x32.
    const int lane = t & 63;
    const int w = t >> 6;
    const int arow = w * 16 + (lane & 15);
    const int ko = (lane >> 4) * 8;
    const int ncol = lane & 15;

    f32x4 acc[8];
    #pragma unroll
    for (int i = 0; i < 8; ++i) acc[i] = (f32x4){0.f, 0.f, 0.f, 0.f};

    #pragma unroll
    for (int kk = 0; kk < 8; ++kk) {
        bf16x8 af = *(const bf16x8*)&As[arow][kk * 32 + ko];
        #pragma unroll
        for (int ct = 0; ct < 8; ++ct) {
            const unsigned short* wp = Wb + (ct * 16 + ncol) * 256 + kk * 32 + ko;
            bf16x8 bf = *(const bf16x8*)wp;
            acc[ct] = __builtin_amdgcn_mfma_f32_16x16x32_bf16(af, bf, acc[ct], 0, 0, 0);
        }
    }

    // C/D: col = lane&15, row = (lane>>4)*4 + r
    const int mr = rowBase + w * 16 + (lane >> 4) * 4;
    if (OUT_BF16) {
        unsigned short* out = (unsigned short*)out_v;
        #pragma unroll
        for (int ct = 0; ct < 8; ++ct) {
            #pragma unroll
            for (int r = 0; r < 4; ++r) {
                out[(size_t)(mr + r) * 128 + ct * 16 + ncol] = f2bf(fmaxf(acc[ct][r], 0.f));
            }
        }
    } else {
        float* out = (float*)out_v;
        #pragma unroll
        for (int ct = 0; ct < 8; ++ct) {
            #pragma unroll
            for (int r = 0; r < 4; ++r) {
                out[(size_t)(mr + r) * 128 + ct * 16 + ncol] = fmaxf(acc[ct][r], 0.f);
            }
        }
    }
}

// ---- Fallback (f32-source) layer kernel, used only if ws is too small ----
template<bool SRC_BF16, bool OUT_BF16>
__global__ __launch_bounds__(256, 2)
void sage_layer(const void* __restrict__ src_v,
                const unsigned short* __restrict__ Wb,
                const int* __restrict__ self_idx,
                const int* __restrict__ neigh_idx,
                void* __restrict__ out_v) {
    __shared__ unsigned short As[64][264];
    __shared__ int sIdx[64];
    __shared__ int nIdx[64][10];

    const int t = threadIdx.x;
    const int rowBase = blockIdx.x * 64;

    if (t < 64) sIdx[t] = self_idx[rowBase + t];
    for (int i = t; i < 640; i += 256) nIdx[i / 10][i % 10] = neigh_idx[rowBase * 10 + i];
    __syncthreads();

    #pragma unroll
    for (int it = 0; it < 16; ++it) {
        int c = it * 256 + t;
        int row = c >> 6;
        int cc = c & 63;
        float4 v;
        if (cc < 32) {
            if constexpr (SRC_BF16) {
                ushort4 u = *(const ushort4*)((const unsigned short*)src_v + (size_t)sIdx[row] * 128 + cc * 4);
                v.x = bf2f(u.x); v.y = bf2f(u.y); v.z = bf2f(u.z); v.w = bf2f(u.w);
            } else {
                v = *(const float4*)((const float*)src_v + (size_t)sIdx[row] * 128 + cc * 4);
            }
        } else {
            int fo = (cc - 32) * 4;
            float sx = 0.f, sy = 0.f, sz = 0.f, sw = 0.f;
            #pragma unroll
            for (int sn = 0; sn < 10; ++sn) {
                float4 x;
                if constexpr (SRC_BF16) {
                    ushort4 u = *(const ushort4*)((const unsigned short*)src_v + (size_t)nIdx[row][sn] * 128 + fo);
                    x.x = bf2f(u.x); x.y = bf2f(u.y); x.z = bf2f(u.z); x.w = bf2f(u.w);
                } else {
                    x = *(const float4*)((const float*)src_v + (size_t)nIdx[row][sn] * 128 + fo);
                }
                sx += x.x; sy += x.y; sz += x.z; sw += x.w;
            }
            v.x = sx * 0.1f; v.y = sy * 0.1f; v.z = sz * 0.1f; v.w = sw * 0.1f;
        }
        ushort4 o;
        o.x = f2bf(v.x); o.y = f2bf(v.y); o.z = f2bf(v.z); o.w = f2bf(v.w);
        *(ushort4*)&As[row][cc * 4] = o;
    }
    __syncthreads();

    const int lane = t & 63;
    const int w = t >> 6;
    const int arow = w * 16 + (lane & 15);
    const int ko = (lane >> 4) * 8;
    const int ncol = lane & 15;

    f32x4 acc[8];
    #pragma unroll
    for (int i = 0; i < 8; ++i) acc[i] = (f32x4){0.f, 0.f, 0.f, 0.f};

    #pragma unroll
    for (int kk = 0; kk < 8; ++kk) {
        bf16x8 af = *(const bf16x8*)&As[arow][kk * 32 + ko];
        #pragma unroll
        for (int ct = 0; ct < 8; ++ct) {
            const unsigned short* wp = Wb + (ct * 16 + ncol) * 256 + kk * 32 + ko;
            bf16x8 bf = *(const bf16x8*)wp;
            acc[ct] = __builtin_amdgcn_mfma_f32_16x16x32_bf16(af, bf, acc[ct], 0, 0, 0);
        }
    }

    const int mr = rowBase + w * 16 + (lane >> 4) * 4;
    if (OUT_BF16) {
        unsigned short* out = (unsigned short*)out_v;
        #pragma unroll
        for (int ct = 0; ct < 8; ++ct) {
            #pragma unroll
            for (int r = 0; r < 4; ++r) {
                out[(size_t)(mr + r) * 128 + ct * 16 + ncol] = f2bf(fmaxf(acc[ct][r], 0.f));
            }
        }
    } else {
        float* out = (float*)out_v;
        #pragma unroll
        for (int ct = 0; ct < 8; ++ct) {
            #pragma unroll
            for (int r = 0; r < 4; ++r) {
                out[(size_t)(mr + r) * 128 + ct * 16 + ncol] = fmaxf(acc[ct][r], 0.f);
            }
        }
    }
}

extern "C" void kernel_launch(void* const* d_in, const int* in_sizes, int n_in,
                              void* d_out, int out_size, void* d_ws, size_t ws_size,
                              hipStream_t stream) {
    const float* raw   = (const float*)d_in[0];   // [200000,128]
    const float* W1    = (const float*)d_in[1];   // [128,256]
    const float* W2    = (const float*)d_in[2];   // [128,256]
    const int* self1   = (const int*)d_in[3];     // [81920]
    const int* neigh1  = (const int*)d_in[4];     // [81920,10]
    const int* self2   = (const int*)d_in[5];     // [8192]
    const int* neigh2  = (const int*)d_in[6];     // [8192,10]
    float* out = (float*)d_out;                   // [8192,128] f32

    char* ws = (char*)d_ws;
    unsigned short* W1b  = (unsigned short*)ws;                        // 128*256
    unsigned short* W2b  = W1b + 128 * 256;                            // 128*256
    unsigned short* h1   = W2b + 128 * 256;                            // 81920*128
    unsigned short* rawb = h1 + (size_t)81920 * 128;                   // 200000*128
    const size_t need = (size_t)(128 * 256 * 2 + 81920 * 128 + (size_t)200000 * 128) * 2;

    cvt_weights<<<128, 256, 0, stream>>>(W1, W2, W1b, W2b);

    if (ws_size >= need) {
        cvt_feat<<<12500, 256, 0, stream>>>(raw, rawb);
        sage_layer_bf<true><<<81920 / 64, 256, 0, stream>>>(
            rawb, W1b, self1, neigh1, (void*)h1);
        sage_layer_bf<false><<<8192 / 64, 256, 0, stream>>>(
            h1, W2b, self2, neigh2, (void*)out);
    } else {
        sage_layer<false, true><<<81920 / 64, 256, 0, stream>>>(
            (const void*)raw, W1b, self1, neigh1, (void*)h1);
        sage_layer<true, false><<<8192 / 64, 256, 0, stream>>>(
            (const void*)h1, W2b, self2, neigh2, (void*)out);
    }
}

// Round 3
// 89.095 us; speedup vs baseline: 1.6643x; 1.2454x over previous
//
#include <hip/hip_runtime.h>
#include <hip/hip_bf16.h>

typedef __attribute__((ext_vector_type(4))) float f32x4;
typedef __attribute__((ext_vector_type(8))) short bf16x8;

__device__ __forceinline__ unsigned short f2bf(float f) {
    unsigned int u = __float_as_uint(f);
    u = (u + 0x7FFFu + ((u >> 16) & 1u)) >> 16;
    return (unsigned short)u;
}

__device__ __forceinline__ float bf2f(unsigned short u) {
    return __uint_as_float(((unsigned int)u) << 16);
}

// Fused conversion: blocks [0,12500) convert features (200000*128 f32 -> bf16),
// blocks [12500,12628) convert W1|W2 (2*128*256).
__global__ __launch_bounds__(256) void cvt_fused(const float* __restrict__ feat,
                                                 const float* __restrict__ W1,
                                                 const float* __restrict__ W2,
                                                 unsigned short* __restrict__ featb,
                                                 unsigned short* __restrict__ W1b,
                                                 unsigned short* __restrict__ W2b) {
    if (blockIdx.x < 12500) {
        size_t i = ((size_t)blockIdx.x * 256 + threadIdx.x) * 8;
        float4 a = *(const float4*)(feat + i);
        float4 b = *(const float4*)(feat + i + 4);
        bf16x8 o;
        o[0] = (short)f2bf(a.x); o[1] = (short)f2bf(a.y);
        o[2] = (short)f2bf(a.z); o[3] = (short)f2bf(a.w);
        o[4] = (short)f2bf(b.x); o[5] = (short)f2bf(b.y);
        o[6] = (short)f2bf(b.z); o[7] = (short)f2bf(b.w);
        *(bf16x8*)(featb + i) = o;
    } else {
        int i = (blockIdx.x - 12500) * 256 + threadIdx.x;   // [0, 32768)
        W1b[i] = f2bf(W1[i]);
        W2b[i] = f2bf(W2[i]);
    }
}

// Fused layer, bf16 source table: out[m] = relu([src[self[m]] | mean_s src[neigh[m][s]]] @ W^T)
// 32 rows/block, 256 threads, K=256, N=128. Each thread owns 2 (row,chunk) pairs
// and issues all 22 gather loads before consuming any (MLP ~22x16B/thread).
template<bool OUT_BF16>
__global__ __launch_bounds__(256, 4)
void sage_layer32(const unsigned short* __restrict__ src,   // [*,128] bf16
                  const unsigned short* __restrict__ Wb,    // [128][256] bf16 row-major
                  const int* __restrict__ self_idx,
                  const int* __restrict__ neigh_idx,
                  void* __restrict__ out_v) {
    __shared__ unsigned short As[32][264];   // [self|agg] rows, +8 pad (row 528B)
    __shared__ int sIdx[32];
    __shared__ int nIdx[320];

    const int t = threadIdx.x;
    const int rowBase = blockIdx.x * 32;

    if (t < 32) sIdx[t] = self_idx[rowBase + t];
    for (int i = t; i < 320; i += 256) nIdx[i] = neigh_idx[rowBase * 10 + i];
    __syncthreads();

    const int r0 = t >> 4;          // rows 0..15
    const int r1 = r0 + 16;         // rows 16..31
    const int co = (t & 15) * 8;    // bf16 chunk offset within a 128-wide row

    // Issue ALL gather loads first: 2 self + 20 neighbor 16B loads in flight.
    bf16x8 sv0 = *(const bf16x8*)(src + (size_t)sIdx[r0] * 128 + co);
    bf16x8 sv1 = *(const bf16x8*)(src + (size_t)sIdx[r1] * 128 + co);
    bf16x8 nv0[10], nv1[10];
    #pragma unroll
    for (int sn = 0; sn < 10; ++sn)
        nv0[sn] = *(const bf16x8*)(src + (size_t)nIdx[r0 * 10 + sn] * 128 + co);
    #pragma unroll
    for (int sn = 0; sn < 10; ++sn)
        nv1[sn] = *(const bf16x8*)(src + (size_t)nIdx[r1 * 10 + sn] * 128 + co);

    // Consume in load order (vmcnt drains incrementally, tail loads stay in flight).
    *(bf16x8*)&As[r0][co] = sv0;
    *(bf16x8*)&As[r1][co] = sv1;

    float s0[8], s1[8];
    #pragma unroll
    for (int e = 0; e < 8; ++e) { s0[e] = 0.f; s1[e] = 0.f; }
    #pragma unroll
    for (int sn = 0; sn < 10; ++sn) {
        #pragma unroll
        for (int e = 0; e < 8; ++e) s0[e] += bf2f((unsigned short)nv0[sn][e]);
    }
    #pragma unroll
    for (int sn = 0; sn < 10; ++sn) {
        #pragma unroll
        for (int e = 0; e < 8; ++e) s1[e] += bf2f((unsigned short)nv1[sn][e]);
    }
    bf16x8 o0, o1;
    #pragma unroll
    for (int e = 0; e < 8; ++e) {
        o0[e] = (short)f2bf(s0[e] * 0.1f);
        o1[e] = (short)f2bf(s1[e] * 0.1f);
    }
    *(bf16x8*)&As[r0][128 + co] = o0;
    *(bf16x8*)&As[r1][128 + co] = o1;
    __syncthreads();

    // MFMA: wave w -> rows (w&1)*16..+16, cols (w>>1)*64..+64. K=256 via 8 steps.
    const int lane = t & 63;
    const int w = t >> 6;
    const int rows16 = (w & 1) * 16;
    const int cols64 = (w >> 1) * 64;
    const int arow = rows16 + (lane & 15);
    const int ko = (lane >> 4) * 8;
    const int ncol = lane & 15;

    f32x4 acc[4];
    #pragma unroll
    for (int i = 0; i < 4; ++i) acc[i] = (f32x4){0.f, 0.f, 0.f, 0.f};

    #pragma unroll
    for (int kk = 0; kk < 8; ++kk) {
        bf16x8 af = *(const bf16x8*)&As[arow][kk * 32 + ko];
        #pragma unroll
        for (int ct = 0; ct < 4; ++ct) {
            const unsigned short* wp = Wb + (size_t)(cols64 + ct * 16 + ncol) * 256 + kk * 32 + ko;
            bf16x8 bf = *(const bf16x8*)wp;
            acc[ct] = __builtin_amdgcn_mfma_f32_16x16x32_bf16(af, bf, acc[ct], 0, 0, 0);
        }
    }

    // C/D: col = lane&15, row = (lane>>4)*4 + r
    const int mr = rowBase + rows16 + (lane >> 4) * 4;
    if (OUT_BF16) {
        unsigned short* out = (unsigned short*)out_v;
        #pragma unroll
        for (int ct = 0; ct < 4; ++ct) {
            #pragma unroll
            for (int r = 0; r < 4; ++r) {
                out[(size_t)(mr + r) * 128 + cols64 + ct * 16 + ncol] = f2bf(fmaxf(acc[ct][r], 0.f));
            }
        }
    } else {
        float* out = (float*)out_v;
        #pragma unroll
        for (int ct = 0; ct < 4; ++ct) {
            #pragma unroll
            for (int r = 0; r < 4; ++r) {
                out[(size_t)(mr + r) * 128 + cols64 + ct * 16 + ncol] = fmaxf(acc[ct][r], 0.f);
            }
        }
    }
}

// ---- Fallback (f32-source) layer kernel, used only if ws is too small ----
template<bool SRC_BF16, bool OUT_BF16>
__global__ __launch_bounds__(256, 2)
void sage_layer(const void* __restrict__ src_v,
                const unsigned short* __restrict__ Wb,
                const int* __restrict__ self_idx,
                const int* __restrict__ neigh_idx,
                void* __restrict__ out_v) {
    __shared__ unsigned short As[64][264];
    __shared__ int sIdx[64];
    __shared__ int nIdx[64][10];

    const int t = threadIdx.x;
    const int rowBase = blockIdx.x * 64;

    if (t < 64) sIdx[t] = self_idx[rowBase + t];
    for (int i = t; i < 640; i += 256) nIdx[i / 10][i % 10] = neigh_idx[rowBase * 10 + i];
    __syncthreads();

    #pragma unroll
    for (int it = 0; it < 16; ++it) {
        int c = it * 256 + t;
        int row = c >> 6;
        int cc = c & 63;
        float4 v;
        if (cc < 32) {
            if constexpr (SRC_BF16) {
                ushort4 u = *(const ushort4*)((const unsigned short*)src_v + (size_t)sIdx[row] * 128 + cc * 4);
                v.x = bf2f(u.x); v.y = bf2f(u.y); v.z = bf2f(u.z); v.w = bf2f(u.w);
            } else {
                v = *(const float4*)((const float*)src_v + (size_t)sIdx[row] * 128 + cc * 4);
            }
        } else {
            int fo = (cc - 32) * 4;
            float sx = 0.f, sy = 0.f, sz = 0.f, sw = 0.f;
            #pragma unroll
            for (int sn = 0; sn < 10; ++sn) {
                float4 x;
                if constexpr (SRC_BF16) {
                    ushort4 u = *(const ushort4*)((const unsigned short*)src_v + (size_t)nIdx[row][sn] * 128 + fo);
                    x.x = bf2f(u.x); x.y = bf2f(u.y); x.z = bf2f(u.z); x.w = bf2f(u.w);
                } else {
                    x = *(const float4*)((const float*)src_v + (size_t)nIdx[row][sn] * 128 + fo);
                }
                sx += x.x; sy += x.y; sz += x.z; sw += x.w;
            }
            v.x = sx * 0.1f; v.y = sy * 0.1f; v.z = sz * 0.1f; v.w = sw * 0.1f;
        }
        ushort4 o;
        o.x = f2bf(v.x); o.y = f2bf(v.y); o.z = f2bf(v.z); o.w = f2bf(v.w);
        *(ushort4*)&As[row][cc * 4] = o;
    }
    __syncthreads();

    const int lane = t & 63;
    const int w = t >> 6;
    const int arow = w * 16 + (lane & 15);
    const int ko = (lane >> 4) * 8;
    const int ncol = lane & 15;

    f32x4 acc[8];
    #pragma unroll
    for (int i = 0; i < 8; ++i) acc[i] = (f32x4){0.f, 0.f, 0.f, 0.f};

    #pragma unroll
    for (int kk = 0; kk < 8; ++kk) {
        bf16x8 af = *(const bf16x8*)&As[arow][kk * 32 + ko];
        #pragma unroll
        for (int ct = 0; ct < 8; ++ct) {
            const unsigned short* wp = Wb + (ct * 16 + ncol) * 256 + kk * 32 + ko;
            bf16x8 bf = *(const bf16x8*)wp;
            acc[ct] = __builtin_amdgcn_mfma_f32_16x16x32_bf16(af, bf, acc[ct], 0, 0, 0);
        }
    }

    const int mr = rowBase + w * 16 + (lane >> 4) * 4;
    if (OUT_BF16) {
        unsigned short* out = (unsigned short*)out_v;
        #pragma unroll
        for (int ct = 0; ct < 8; ++ct) {
            #pragma unroll
            for (int r = 0; r < 4; ++r) {
                out[(size_t)(mr + r) * 128 + ct * 16 + ncol] = f2bf(fmaxf(acc[ct][r], 0.f));
            }
        }
    } else {
        float* out = (float*)out_v;
        #pragma unroll
        for (int ct = 0; ct < 8; ++ct) {
            #pragma unroll
            for (int r = 0; r < 4; ++r) {
                out[(size_t)(mr + r) * 128 + ct * 16 + ncol] = fmaxf(acc[ct][r], 0.f);
            }
        }
    }
}

extern "C" void kernel_launch(void* const* d_in, const int* in_sizes, int n_in,
                              void* d_out, int out_size, void* d_ws, size_t ws_size,
                              hipStream_t stream) {
    const float* raw   = (const float*)d_in[0];   // [200000,128]
    const float* W1    = (const float*)d_in[1];   // [128,256]
    const float* W2    = (const float*)d_in[2];   // [128,256]
    const int* self1   = (const int*)d_in[3];     // [81920]
    const int* neigh1  = (const int*)d_in[4];     // [81920,10]
    const int* self2   = (const int*)d_in[5];     // [8192]
    const int* neigh2  = (const int*)d_in[6];     // [8192,10]
    float* out = (float*)d_out;                   // [8192,128] f32

    char* ws = (char*)d_ws;
    unsigned short* W1b  = (unsigned short*)ws;                        // 128*256
    unsigned short* W2b  = W1b + 128 * 256;                            // 128*256
    unsigned short* h1   = W2b + 128 * 256;                            // 81920*128
    unsigned short* rawb = h1 + (size_t)81920 * 128;                   // 200000*128
    const size_t need = (size_t)(128 * 256 * 2 + 81920 * 128 + (size_t)200000 * 128) * 2;

    if (ws_size >= need) {
        cvt_fused<<<12628, 256, 0, stream>>>(raw, W1, W2, rawb, W1b, W2b);
        sage_layer32<true><<<81920 / 32, 256, 0, stream>>>(
            rawb, W1b, self1, neigh1, (void*)h1);
        sage_layer32<false><<<8192 / 32, 256, 0, stream>>>(
            h1, W2b, self2, neigh2, (void*)out);
    } else {
        cvt_fused<<<12628, 256, 0, stream>>>(raw, W1, W2, rawb, W1b, W2b);  // rawb unused below
        sage_layer<false, true><<<81920 / 64, 256, 0, stream>>>(
            (const void*)raw, W1b, self1, neigh1, (void*)h1);
        sage_layer<true, false><<<8192 / 64, 256, 0, stream>>>(
            (const void*)h1, W2b, self2, neigh2, (void*)out);
    }
}